// Round 4
// baseline (274.799 us; speedup 1.0000x reference)
//
#include <hip/hip_runtime.h>
#include <math.h>

// LocalContrastNormalization: out = sigmoid(0.5*(x-mu)/(sigma+eps)),
// mu/sigma from 31x31 zero-padded box filter (separable).
// v4: BARRIER-FREE wave-autonomous design. Each wave owns an 8-row strip and
// a private LDS row-buffer; vertical box = per-lane register sliding window
// over 16 columns (whole row covered by one wave); horizontal box = per-lane
// register sliding window over its 16 contiguous cols, reading packed
// (sum,sumsq) float2 from a transposed LDS layout (all offsets compile-time,
// lanes consecutive -> 2-way bank aliasing only = free). Zero __syncthreads:
// correctness relies only on intra-wave LDS ordering (explicit lgkmcnt(0)
// between publish and read). Slide global loads issued early (T14 split) so
// HBM latency hides under the LDS/VALU horizontal phase.

#define KSZ   31
#define PAD   15
#define IMG_H 1024
#define IMG_W 1024
#define RPW   8                  // rows per wave
#define WPB   4                  // waves per block
#define SH    (RPW * WPB)        // 32 rows per block
#define NT    256
#define LROW  66                 // transposed stride in float2 units
#define LBUF  (16 * LROW)        // 1056 float2 per wave buffer
#define EPSV  1e-5f

__global__ __launch_bounds__(NT, 4)
void lcn_fused_kernel(const float* __restrict__ x, float* __restrict__ out) {
    // XCD-aware bijective swizzle (gridDim.x % 8 == 0): consecutive chunks
    // (same image, adjacent y) land on the same XCD -> halo re-reads L2-hit.
    const int cpx = gridDim.x >> 3;
    const int bid = (blockIdx.x & 7) * cpx + (blockIdx.x >> 3);

    const int chunk = bid & 31;            // 32 chunks of 32 rows per image
    const int b     = bid >> 5;
    const int y0    = chunk * SH;

    const float* img  = x   + (size_t)b * (IMG_H * IMG_W);
    float*       oimg = out + (size_t)b * (IMG_H * IMG_W);

    __shared__ float2 vbuf[WPB][LBUF];

    const int t    = threadIdx.x;
    const int wave = t >> 6;
    const int lane = t & 63;
    float2* vb = vbuf[wave];               // wave-private buffer

    // Zero the pads (iv 0..15 -> phys iv*66; iv 1040..1055 -> (iv&15)*66+65).
    // Interior is rewritten every row. Intra-wave: no barrier needed.
    if (lane < 16) {
        vb[lane * LROW]            = make_float2(0.f, 0.f);
        vb[lane * LROW + LROW - 1] = make_float2(0.f, 0.f);
    }

    const int r0 = y0 + wave * RPW;        // this wave's first output row
    const int cv = 4 * lane;               // vertical col base (per 256-group)

    // Vertical running sums for 16 cols: col = 256*j + 4*lane + k.
    float vsA[16], vqA[16];
    #pragma unroll
    for (int i = 0; i < 16; ++i) { vsA[i] = 0.f; vqA[i] = 0.f; }

    for (int y = r0 - PAD; y <= r0 + PAD; ++y) {
        if (y < 0 || y >= IMG_H) continue;
        const float* rp = img + (size_t)y * IMG_W + cv;
        #pragma unroll
        for (int j = 0; j < 4; ++j) {
            float4 v = *(const float4*)(rp + 256 * j);
            vsA[4*j+0] += v.x; vqA[4*j+0] += v.x * v.x;
            vsA[4*j+1] += v.y; vqA[4*j+1] += v.y * v.y;
            vsA[4*j+2] += v.z; vqA[4*j+2] += v.z * v.z;
            vsA[4*j+3] += v.w; vqA[4*j+3] += v.w * v.w;
        }
    }

    // Publish base: iv = 256j + 4*lane + k + 16
    //  -> phys = (4*(lane&3)+k)*66 + (lane>>2) + 1 + 16j  (16j is immediate)
    const int pb = (lane >> 2) + 1;
    const int g0 = 4 * (lane & 3);

    const int   cbase = lane << 4;         // horizontal: 16 contiguous cols
    const float inv   = 1.0f / 961.0f;

    #pragma unroll 1
    for (int r = 0; r < RPW; ++r) {
        const int row = r0 + r;

        // ---- publish window(row) vertical sums ----
        #pragma unroll
        for (int j = 0; j < 4; ++j) {
            vb[(g0 + 0) * LROW + pb + 16 * j] = make_float2(vsA[4*j+0], vqA[4*j+0]);
            vb[(g0 + 1) * LROW + pb + 16 * j] = make_float2(vsA[4*j+1], vqA[4*j+1]);
            vb[(g0 + 2) * LROW + pb + 16 * j] = make_float2(vsA[4*j+2], vqA[4*j+2]);
            vb[(g0 + 3) * LROW + pb + 16 * j] = make_float2(vsA[4*j+3], vqA[4*j+3]);
        }
        // Intra-wave visibility of all 64 lanes' publishes before reads.
        asm volatile("s_waitcnt lgkmcnt(0)" ::: "memory");

        // ---- issue next-row slide loads EARLY (consumed after horizontal) ----
        const int ysub = row - PAD;
        const int yadd = row + PAD + 1;
        const bool do_slide = (r < RPW - 1);
        const bool has_sub  = do_slide && (ysub >= 0);
        const bool has_add  = do_slide && (yadd < IMG_H);
        float4 sb0, sb1, sb2, sb3, ad0, ad1, ad2, ad3;
        if (has_sub) {
            const float* rp = img + (size_t)ysub * IMG_W + cv;
            sb0 = *(const float4*)(rp      );
            sb1 = *(const float4*)(rp + 256);
            sb2 = *(const float4*)(rp + 512);
            sb3 = *(const float4*)(rp + 768);
        }
        if (has_add) {
            const float* rp = img + (size_t)yadd * IMG_W + cv;
            ad0 = *(const float4*)(rp      );
            ad1 = *(const float4*)(rp + 256);
            ad2 = *(const float4*)(rp + 512);
            ad3 = *(const float4*)(rp + 768);
        }

        // ---- horizontal sliding window + pointwise ----
        const float2* vr = vb + lane;      // phys = (s&15)*66 + (s>>4) + lane
        float hs = 0.f, hq = 0.f;
        #pragma unroll
        for (int s = 1; s <= 31; ++s) {
            float2 v = vr[(s & 15) * LROW + (s >> 4)];
            hs += v.x; hq += v.y;
        }

        const float* xr   = img  + (size_t)row * IMG_W + cbase;
        float*       orow = oimg + (size_t)row * IMG_W + cbase;

        #pragma unroll
        for (int g = 0; g < 4; ++g) {
            float4 xv = ((const float4*)xr)[g];
            float rz[4];
            #pragma unroll
            for (int j4 = 0; j4 < 4; ++j4) {
                const int j = 4 * g + j4;
                if (j > 0) {
                    // add iv=cbase+j+31 -> ((j-1)&15)*66 + 2
                    // sub iv=cbase+j    -> (j&15)*66 + 0
                    float2 va = vr[((j - 1) & 15) * LROW + 2];
                    float2 vsu = vr[(j & 15) * LROW];
                    hs += va.x - vsu.x;
                    hq += va.y - vsu.y;
                }
                const float mean = hs * inv;
                const float var  = fmaf(-mean, mean, hq * inv);
                const float stdv = sqrtf(fmaxf(var, EPSV));
                const float xc   = (j4 == 0) ? xv.x : (j4 == 1) ? xv.y
                                 : (j4 == 2) ? xv.z : xv.w;
                const float norm = (xc - mean) *
                                   __builtin_amdgcn_rcpf(stdv + EPSV);
                const float e    = __expf(-0.5f * norm);
                rz[j4] = __builtin_amdgcn_rcpf(1.0f + e);
            }
            ((float4*)orow)[g] = make_float4(rz[0], rz[1], rz[2], rz[3]);
        }

        // ---- apply vertical slides (loads have had the whole phase) ----
        if (has_sub) {
            vsA[0] -= sb0.x; vqA[0] = fmaf(-sb0.x, sb0.x, vqA[0]);
            vsA[1] -= sb0.y; vqA[1] = fmaf(-sb0.y, sb0.y, vqA[1]);
            vsA[2] -= sb0.z; vqA[2] = fmaf(-sb0.z, sb0.z, vqA[2]);
            vsA[3] -= sb0.w; vqA[3] = fmaf(-sb0.w, sb0.w, vqA[3]);
            vsA[4] -= sb1.x; vqA[4] = fmaf(-sb1.x, sb1.x, vqA[4]);
            vsA[5] -= sb1.y; vqA[5] = fmaf(-sb1.y, sb1.y, vqA[5]);
            vsA[6] -= sb1.z; vqA[6] = fmaf(-sb1.z, sb1.z, vqA[6]);
            vsA[7] -= sb1.w; vqA[7] = fmaf(-sb1.w, sb1.w, vqA[7]);
            vsA[8] -= sb2.x; vqA[8] = fmaf(-sb2.x, sb2.x, vqA[8]);
            vsA[9] -= sb2.y; vqA[9] = fmaf(-sb2.y, sb2.y, vqA[9]);
            vsA[10]-= sb2.z; vqA[10]= fmaf(-sb2.z, sb2.z, vqA[10]);
            vsA[11]-= sb2.w; vqA[11]= fmaf(-sb2.w, sb2.w, vqA[11]);
            vsA[12]-= sb3.x; vqA[12]= fmaf(-sb3.x, sb3.x, vqA[12]);
            vsA[13]-= sb3.y; vqA[13]= fmaf(-sb3.y, sb3.y, vqA[13]);
            vsA[14]-= sb3.z; vqA[14]= fmaf(-sb3.z, sb3.z, vqA[14]);
            vsA[15]-= sb3.w; vqA[15]= fmaf(-sb3.w, sb3.w, vqA[15]);
        }
        if (has_add) {
            vsA[0] += ad0.x; vqA[0] = fmaf(ad0.x, ad0.x, vqA[0]);
            vsA[1] += ad0.y; vqA[1] = fmaf(ad0.y, ad0.y, vqA[1]);
            vsA[2] += ad0.z; vqA[2] = fmaf(ad0.z, ad0.z, vqA[2]);
            vsA[3] += ad0.w; vqA[3] = fmaf(ad0.w, ad0.w, vqA[3]);
            vsA[4] += ad1.x; vqA[4] = fmaf(ad1.x, ad1.x, vqA[4]);
            vsA[5] += ad1.y; vqA[5] = fmaf(ad1.y, ad1.y, vqA[5]);
            vsA[6] += ad1.z; vqA[6] = fmaf(ad1.z, ad1.z, vqA[6]);
            vsA[7] += ad1.w; vqA[7] = fmaf(ad1.w, ad1.w, vqA[7]);
            vsA[8] += ad2.x; vqA[8] = fmaf(ad2.x, ad2.x, vqA[8]);
            vsA[9] += ad2.y; vqA[9] = fmaf(ad2.y, ad2.y, vqA[9]);
            vsA[10]+= ad2.z; vqA[10]= fmaf(ad2.z, ad2.z, vqA[10]);
            vsA[11]+= ad2.w; vqA[11]= fmaf(ad2.w, ad2.w, vqA[11]);
            vsA[12]+= ad3.x; vqA[12]= fmaf(ad3.x, ad3.x, vqA[12]);
            vsA[13]+= ad3.y; vqA[13]= fmaf(ad3.y, ad3.y, vqA[13]);
            vsA[14]+= ad3.z; vqA[14]= fmaf(ad3.z, ad3.z, vqA[14]);
            vsA[15]+= ad3.w; vqA[15]= fmaf(ad3.w, ad3.w, vqA[15]);
        }
        // WAR safety: next row's publishes must not pass this row's reads.
        asm volatile("s_waitcnt lgkmcnt(0)" ::: "memory");
    }
}

extern "C" void kernel_launch(void* const* d_in, const int* in_sizes, int n_in,
                              void* d_out, int out_size, void* d_ws, size_t ws_size,
                              hipStream_t stream) {
    (void)n_in; (void)out_size; (void)d_ws; (void)ws_size;
    const float* x = (const float*)d_in[0];
    float* out = (float*)d_out;
    const int B = in_sizes[0] / (IMG_H * IMG_W);   // 32
    dim3 grid(B * (IMG_H / SH));                   // 1024 blocks
    lcn_fused_kernel<<<grid, NT, 0, stream>>>(x, out);
}

// Round 5
// 144.426 us; speedup vs baseline: 1.9027x; 1.9027x over previous
//
#include <hip/hip_runtime.h>
#include <math.h>

// LocalContrastNormalization: out = sigmoid(0.5*(x-mu)/(sigma+eps)),
// mu/sigma from 31x31 zero-padded box filter (separable).
// v5: R3 block-synchronous structure, tuned for occupancy + MLP.
//  - Half-width blocks: 512 interior cols + 16 halo cols each side.
//    LDS = 4 rows x 552 float2 = 17.7 KB -> 8 blocks/CU, 32 waves/CU.
//  - NT=256 (4 waves), RPP=4 rows/phase, SH=32 rows/block, grid=2048.
//  - All slide loads batched + unconditional (clamp+mask) for MLP.
//  - Transposed LDS layout: horizontal reads are base(lane)+imm, lanes
//    consecutive (conflict-free); 8 cols/lane register sliding window.
//  - Wave-contiguous 2KB x-reads/stores: no sector amplification.

#define KSZ   31
#define PAD   15
#define IMG_H 1024
#define IMG_W 1024
#define CW    512               // interior cols per block
#define SH    32                // rows per block
#define RPP   4                 // rows per phase == waves per block
#define NT    256
#define HALO  16
#define LROW  69                // transposed stride in float2 units (8*69=552)
#define LBUF  (8 * LROW)
#define EPSV  1e-5f

__global__ __launch_bounds__(NT, 8)
void lcn_fused_kernel(const float* __restrict__ x, float* __restrict__ out) {
    // XCD-aware bijective swizzle (gridDim.x = 2048, %8==0): consecutive
    // chunks (same image, adjacent y / same row pair) share an XCD's L2.
    const int cpx = gridDim.x >> 3;
    const int bid = (blockIdx.x & 7) * cpx + (blockIdx.x >> 3);

    const int xc = bid & 1;                 // 2 x-chunks
    const int yc = (bid >> 1) & 31;         // 32 y-chunks
    const int b  = bid >> 6;                // image
    const int y0 = yc * SH;
    const int x0 = xc * CW;

    const float* img  = x   + (size_t)b * (IMG_H * IMG_W);
    float*       oimg = out + (size_t)b * (IMG_H * IMG_W);

    __shared__ float2 vbuf[RPP][LBUF];      // (vsum, vsumsq), transposed

    const int t    = threadIdx.x;
    const int wave = t >> 6;
    const int lane = t & 63;

    // Interior: 2 consecutive cols per thread.
    const int lci = 2 * t;                  // local col 0..510
    const int gci = x0 + lci;

    // Halo: 32 threads (t&7)==0 own one halo col each.
    const bool isH  = (t & 7) == 0;
    const int  hidx = t >> 3;               // 0..31
    const int  gchr = (hidx < 16) ? (x0 - HALO + hidx)
                                  : (x0 + CW + (hidx - 16));
    const bool hval = isH && (gchr >= 0) && (gchr < IMG_W);
    const int  gch  = min(max(gchr, 0), IMG_W - 1);

    // Publish offsets (transposed): phys(iv) = (iv&7)*LROW + (iv>>3)
    const int iv0 = lci + HALO;
    const int wp0 = ((iv0    ) & 7) * LROW + ((iv0    ) >> 3);
    const int wp1 = ((iv0 + 1) & 7) * LROW + ((iv0 + 1) >> 3);
    const int ivh = (hidx < 16) ? hidx : (CW + HALO + (hidx - 16));
    const int wph = (ivh & 7) * LROW + (ivh >> 3);

    // Warm-up: window(y0) = rows [y0-15, y0+15] (upper edge never clips).
    float vs0 = 0.f, vq0 = 0.f, vs1 = 0.f, vq1 = 0.f, hvs = 0.f, hvq = 0.f;
    for (int yy = y0 - PAD; yy <= y0 + PAD; ++yy) {
        const int yyc = max(yy, 0);
        float2 v = *(const float2*)(img + (size_t)yyc * IMG_W + gci);
        const float m = (yy >= 0) ? 1.f : 0.f;
        v.x *= m; v.y *= m;
        vs0 += v.x; vq0 = fmaf(v.x, v.x, vq0);
        vs1 += v.y; vq1 = fmaf(v.y, v.y, vq1);
        if (isH) {
            float h = img[(size_t)yyc * IMG_W + gch];
            h = (hval && yy >= 0) ? h : 0.f;
            hvs += h; hvq = fmaf(h, h, hvq);
        }
    }

    const int   lc0 = lane << 3;            // 8 contiguous cols per lane
    const float inv = 1.0f / 961.0f;

    for (int ph = 0; ph < SH / RPP; ++ph) {
        const int yo = y0 + ph * RPP;

        // ---- batched interior slide loads (8 independent float2) ----
        float2 sb[RPP], ad[RPP];
        #pragma unroll
        for (int r = 0; r < RPP; ++r) {
            const int ys  = yo - PAD + r;
            const int ya  = yo + PAD + 1 + r;
            const int ysc = max(ys, 0);
            const int yac = min(ya, IMG_H - 1);
            float2 vS = *(const float2*)(img + (size_t)ysc * IMG_W + gci);
            float2 vA = *(const float2*)(img + (size_t)yac * IMG_W + gci);
            const float mS = (ys >= 0)    ? 1.f : 0.f;
            const float mA = (ya < IMG_H) ? 1.f : 0.f;
            sb[r] = make_float2(vS.x * mS, vS.y * mS);
            ad[r] = make_float2(vA.x * mA, vA.y * mA);
        }
        // x row for this wave's horizontal phase (prefetched early).
        const int myrow = yo + wave;
        const float* xr = img + (size_t)myrow * IMG_W + x0 + lc0;
        const float4 xva = ((const float4*)xr)[0];
        const float4 xvb = ((const float4*)xr)[1];

        // ---- publish + slide, RPP rows ----
        #pragma unroll
        for (int r = 0; r < RPP; ++r) {
            vbuf[r][wp0] = make_float2(vs0, vq0);
            vbuf[r][wp1] = make_float2(vs1, vq1);
            if (isH) {
                vbuf[r][wph] = make_float2(hvs, hvq);
                const int ys  = yo - PAD + r;
                const int ya  = yo + PAD + 1 + r;
                const int ysc = max(ys, 0);
                const int yac = min(ya, IMG_H - 1);
                float hS = img[(size_t)ysc * IMG_W + gch];
                float hA = img[(size_t)yac * IMG_W + gch];
                hS = (hval && ys >= 0)    ? hS : 0.f;
                hA = (hval && ya < IMG_H) ? hA : 0.f;
                hvs += hA - hS;
                hvq = fmaf(hA, hA, hvq); hvq = fmaf(-hS, hS, hvq);
            }
            vs0 += ad[r].x - sb[r].x;
            vq0 = fmaf(ad[r].x, ad[r].x, vq0); vq0 = fmaf(-sb[r].x, sb[r].x, vq0);
            vs1 += ad[r].y - sb[r].y;
            vq1 = fmaf(ad[r].y, ad[r].y, vq1); vq1 = fmaf(-sb[r].y, sb[r].y, vq1);
        }
        __syncthreads();

        // ---- horizontal sliding window + pointwise (wave -> row yo+wave) ----
        const float2* vr = &vbuf[wave][lane];
        float hs = 0.f, hq = 0.f;
        #pragma unroll
        for (int s = 1; s <= 31; ++s) {       // window for col lc0
            float2 v = vr[(s & 7) * LROW + (s >> 3)];
            hs += v.x; hq += v.y;
        }
        float res[8];
        #pragma unroll
        for (int j = 0; j < 8; ++j) {
            if (j > 0) {
                float2 va  = vr[((j + 31) & 7) * LROW + ((j + 31) >> 3)];
                float2 vb2 = vr[(j & 7) * LROW + (j >> 3)];
                hs += va.x - vb2.x;
                hq += va.y - vb2.y;
            }
            const float mean = hs * inv;
            const float var  = fmaf(-mean, mean, hq * inv);
            const float stdv = sqrtf(fmaxf(var, EPSV));
            const float xcv  = (j==0)?xva.x:(j==1)?xva.y:(j==2)?xva.z:(j==3)?xva.w
                              :(j==4)?xvb.x:(j==5)?xvb.y:(j==6)?xvb.z:xvb.w;
            const float norm = (xcv - mean) * __builtin_amdgcn_rcpf(stdv + EPSV);
            res[j] = __builtin_amdgcn_rcpf(1.0f + __expf(-0.5f * norm));
        }
        float* orow = oimg + (size_t)myrow * IMG_W + x0 + lc0;
        ((float4*)orow)[0] = make_float4(res[0], res[1], res[2], res[3]);
        ((float4*)orow)[1] = make_float4(res[4], res[5], res[6], res[7]);
        __syncthreads();                     // WAR: buffers rewritten next phase
    }
}

extern "C" void kernel_launch(void* const* d_in, const int* in_sizes, int n_in,
                              void* d_out, int out_size, void* d_ws, size_t ws_size,
                              hipStream_t stream) {
    (void)n_in; (void)out_size; (void)d_ws; (void)ws_size;
    const float* x = (const float*)d_in[0];
    float* out = (float*)d_out;
    const int B = in_sizes[0] / (IMG_H * IMG_W);       // 32
    dim3 grid(B * (IMG_H / SH) * (IMG_W / CW));        // 2048 blocks
    lcn_fused_kernel<<<grid, NT, 0, stream>>>(x, out);
}

// Round 6
// 101.110 us; speedup vs baseline: 2.7178x; 1.4284x over previous
//
#include <hip/hip_runtime.h>
#include <math.h>

// LocalContrastNormalization: out = sigmoid(0.5*(x-mu)/(sigma+eps)),
// mu/sigma from 31x31 zero-padded box filter (separable).
// v6: R3 full-width block structure (proven exact 131MB writes) +
//     batched clamp+mask slide loads + CROSS-PHASE prefetch:
//     phase ph's slide rows and x-row are loaded during phase ph-1's
//     horizontal compute (issue-early / consume-after-next-barrier).
//  - CW=1024 (full rows), NT=256 (4 waves), RPP=4 rows/phase, SH=32,
//    grid=1024 (4 blocks/CU, fully resident), LDS 33.8 KB.
//  - Transposed LDS layout: horizontal reads are base(lane)+imm,
//    lanes consecutive -> 2-way bank aliasing only.

#define KSZ    31
#define PAD    15
#define IMG_H  1024
#define IMG_W  1024
#define SH     32                // rows per block
#define RPP    4                 // rows per phase == waves per block
#define PHASES (SH / RPP)        // 8
#define NT     256
#define LROW   66                // transposed stride in float2 units
#define LBUF   (16 * LROW)       // 1056 float2 per row-buffer
#define EPSV   1e-5f

__global__ __launch_bounds__(NT, 4)
void lcn_fused_kernel(const float* __restrict__ x, float* __restrict__ out) {
    // XCD-aware bijective swizzle (gridDim.x = 1024, %8==0): consecutive
    // chunks (same image, adjacent y) share an XCD's L2 for halo re-reads.
    const int cpx = gridDim.x >> 3;
    const int bid = (blockIdx.x & 7) * cpx + (blockIdx.x >> 3);

    const int chunk = bid & 31;            // 32 chunks of 32 rows per image
    const int b     = bid >> 5;
    const int y0    = chunk * SH;

    const float* img  = x   + (size_t)b * (IMG_H * IMG_W);
    float*       oimg = out + (size_t)b * (IMG_H * IMG_W);

    __shared__ float2 vbuf[RPP][LBUF];     // (vsum, vsumsq), transposed

    const int t    = threadIdx.x;
    const int wave = t >> 6;
    const int lane = t & 63;

    // Zero only the pads: iv in [0,16) -> phys iv*66; iv in [1040,1056)
    // -> phys (iv&15)*66 + 65. Interior is republished every phase.
    for (int i = t; i < RPP * 32; i += NT) {
        const int r = i >> 5, k = i & 31;
        float2* vb = vbuf[r];
        if (k < 16) vb[k * LROW] = make_float2(0.f, 0.f);
        else        vb[(k - 16) * LROW + (LROW - 1)] = make_float2(0.f, 0.f);
    }

    // ---- vertical warm-up: window(y0) over rows [y0-15, y0+15] ----
    const int c0 = 4 * t;                  // 4 consecutive cols per thread
    float vs0 = 0.f, vs1 = 0.f, vs2 = 0.f, vs3 = 0.f;
    float vq0 = 0.f, vq1 = 0.f, vq2 = 0.f, vq3 = 0.f;
    for (int y = y0 - PAD; y <= y0 + PAD; ++y) {   // top never clips
        const int yc = max(y, 0);
        float4 v = *(const float4*)(img + (size_t)yc * IMG_W + c0);
        const float m = (y >= 0) ? 1.f : 0.f;
        v.x *= m; v.y *= m; v.z *= m; v.w *= m;
        vs0 += v.x; vq0 = fmaf(v.x, v.x, vq0);
        vs1 += v.y; vq1 = fmaf(v.y, v.y, vq1);
        vs2 += v.z; vq2 = fmaf(v.z, v.z, vq2);
        vs3 += v.w; vq3 = fmaf(v.w, v.w, vq3);
    }

    // Transposed publish indices for iv = c0+16+k.
    int wp0, wp1, wp2, wp3;
    {
        const int iv = c0 + 16;
        wp0 = ((iv    ) & 15) * LROW + ((iv    ) >> 4);
        wp1 = ((iv + 1) & 15) * LROW + ((iv + 1) >> 4);
        wp2 = ((iv + 2) & 15) * LROW + ((iv + 2) >> 4);
        wp3 = ((iv + 3) & 15) * LROW + ((iv + 3) >> 4);
    }

    const int   cbase = lane << 4;         // horizontal: 16 contiguous cols
    const float inv   = 1.0f / 961.0f;

    // ---- phase-0 prefetch: slide rows + x row ----
    float4 sb[RPP], ad[RPP];               // sub/add rows for this phase
    float4 xa, xb, xc, xd;                 // x row for this wave, this phase
    {
        #pragma unroll
        for (int r = 0; r < RPP; ++r) {
            const int ys = y0 + r - PAD;
            const int ya = y0 + r + PAD + 1;
            const int ysc = max(ys, 0);
            float4 vS = *(const float4*)(img + (size_t)ysc * IMG_W + c0);
            float4 vA = *(const float4*)(img + (size_t)ya  * IMG_W + c0);
            const float mS = (ys >= 0) ? 1.f : 0.f;   // ya < H always at ph0
            vS.x *= mS; vS.y *= mS; vS.z *= mS; vS.w *= mS;
            sb[r] = vS; ad[r] = vA;
        }
        const float* xr = img + (size_t)(y0 + wave) * IMG_W + cbase;
        xa = ((const float4*)xr)[0]; xb = ((const float4*)xr)[1];
        xc = ((const float4*)xr)[2]; xd = ((const float4*)xr)[3];
    }

    __syncthreads();   // orders pad-init (and nothing else) before reads

    for (int ph = 0; ph < PHASES; ++ph) {
        const int yo = y0 + ph * RPP;

        // ---- publish + apply prefetched slides, RPP rows ----
        #pragma unroll
        for (int r = 0; r < RPP; ++r) {
            vbuf[r][wp0] = make_float2(vs0, vq0);
            vbuf[r][wp1] = make_float2(vs1, vq1);
            vbuf[r][wp2] = make_float2(vs2, vq2);
            vbuf[r][wp3] = make_float2(vs3, vq3);
            vs0 += ad[r].x - sb[r].x;
            vq0 = fmaf(ad[r].x, ad[r].x, vq0); vq0 = fmaf(-sb[r].x, sb[r].x, vq0);
            vs1 += ad[r].y - sb[r].y;
            vq1 = fmaf(ad[r].y, ad[r].y, vq1); vq1 = fmaf(-sb[r].y, sb[r].y, vq1);
            vs2 += ad[r].z - sb[r].z;
            vq2 = fmaf(ad[r].z, ad[r].z, vq2); vq2 = fmaf(-sb[r].z, sb[r].z, vq2);
            vs3 += ad[r].w - sb[r].w;
            vq3 = fmaf(ad[r].w, ad[r].w, vq3); vq3 = fmaf(-sb[r].w, sb[r].w, vq3);
        }
        __syncthreads();

        // ---- issue NEXT phase's loads (consumed after next barrier) ----
        if (ph < PHASES - 1) {
            const int yn = yo + RPP;
            #pragma unroll
            for (int r = 0; r < RPP; ++r) {
                const int ys = yn + r - PAD;
                const int ya = yn + r + PAD + 1;
                const int ysc = max(ys, 0);
                const int yac = min(ya, IMG_H - 1);
                float4 vS = *(const float4*)(img + (size_t)ysc * IMG_W + c0);
                float4 vA = *(const float4*)(img + (size_t)yac * IMG_W + c0);
                const float mS = (ys >= 0)    ? 1.f : 0.f;
                const float mA = (ya < IMG_H) ? 1.f : 0.f;
                vS.x *= mS; vS.y *= mS; vS.z *= mS; vS.w *= mS;
                vA.x *= mA; vA.y *= mA; vA.z *= mA; vA.w *= mA;
                sb[r] = vS; ad[r] = vA;
            }
        }
        float4 nxa, nxb, nxc, nxd;
        if (ph < PHASES - 1) {
            const float* xr = img + (size_t)(yo + RPP + wave) * IMG_W + cbase;
            nxa = ((const float4*)xr)[0]; nxb = ((const float4*)xr)[1];
            nxc = ((const float4*)xr)[2]; nxd = ((const float4*)xr)[3];
        }

        // ---- horizontal sliding window + pointwise (wave -> row yo+wave) ----
        {
            const float2* vr = &vbuf[wave][lane];
            float hs = 0.f, hq = 0.f;
            #pragma unroll
            for (int s = 1; s <= 31; ++s) {
                float2 v = vr[(s & 15) * LROW + (s >> 4)];
                hs += v.x; hq += v.y;
            }
            float xs[16] = { xa.x, xa.y, xa.z, xa.w,  xb.x, xb.y, xb.z, xb.w,
                             xc.x, xc.y, xc.z, xc.w,  xd.x, xd.y, xd.z, xd.w };
            float res[16];
            #pragma unroll
            for (int j = 0; j < 16; ++j) {
                if (j > 0) {
                    float2 va  = vr[((j - 1) & 15) * LROW + 2];
                    float2 vsu = vr[(j & 15) * LROW];
                    hs += va.x - vsu.x;
                    hq += va.y - vsu.y;
                }
                const float mean = hs * inv;
                const float var  = fmaf(-mean, mean, hq * inv);
                const float stdv = sqrtf(fmaxf(var, EPSV));
                const float norm = (xs[j] - mean) *
                                   __builtin_amdgcn_rcpf(stdv + EPSV);
                res[j] = __builtin_amdgcn_rcpf(1.0f + __expf(-0.5f * norm));
            }
            float* orow = oimg + (size_t)(yo + wave) * IMG_W + cbase;
            ((float4*)orow)[0] = make_float4(res[0],  res[1],  res[2],  res[3]);
            ((float4*)orow)[1] = make_float4(res[4],  res[5],  res[6],  res[7]);
            ((float4*)orow)[2] = make_float4(res[8],  res[9],  res[10], res[11]);
            ((float4*)orow)[3] = make_float4(res[12], res[13], res[14], res[15]);
        }

        xa = nxa; xb = nxb; xc = nxc; xd = nxd;
        __syncthreads();                   // WAR: buffers rewritten next phase
    }
}

extern "C" void kernel_launch(void* const* d_in, const int* in_sizes, int n_in,
                              void* d_out, int out_size, void* d_ws, size_t ws_size,
                              hipStream_t stream) {
    (void)n_in; (void)out_size; (void)d_ws; (void)ws_size;
    const float* x = (const float*)d_in[0];
    float* out = (float*)d_out;
    const int B = in_sizes[0] / (IMG_H * IMG_W);   // 32
    dim3 grid(B * (IMG_H / SH));                   // 1024 blocks
    lcn_fused_kernel<<<grid, NT, 0, stream>>>(x, out);
}

// Round 7
// 89.669 us; speedup vs baseline: 3.0646x; 1.1276x over previous
//
#include <hip/hip_runtime.h>
#include <math.h>

// LocalContrastNormalization: out = sigmoid(0.5*(x-mu)/(sigma+eps)),
// mu/sigma from 31x31 zero-padded box filter (separable).
// v7: R3's proven block-synchronous structure (exact-131MB store pattern,
// transposed LDS, within-phase loads) scaled to SH=64 to amortize the
// vertical halo: FETCH ~= (SH+30)/SH * 128MB -> 1.47x instead of 1.94x.
//  - NT=512 (8 waves), RPP=8 rows/phase, 8 phases, grid=512 (2 blocks/CU,
//    fully resident, 16 waves/CU). LDS = 8 x 1056 float2 = 67.6 KB.
//  - Vertical: 2 cols/thread register sliding window; slide loads batched
//    branch-free (clamp+mask) at phase start -> 16 outstanding loads/thread.
//  - Horizontal: per-lane 16-col register sliding window over transposed
//    (sum,sumsq) float2 LDS; all offsets compile-time, lanes consecutive.
//  - NO cross-phase prefetch (R6 regression: VGPR/occupancy cost).

#define KSZ    31
#define PAD    15
#define IMG_H  1024
#define IMG_W  1024
#define SH     64                // rows per block
#define RPP    8                 // rows per phase == waves per block
#define PHASES (SH / RPP)        // 8
#define NT     512
#define LROW   66                // transposed stride in float2 units
#define LBUF   (16 * LROW)       // 1056 float2 per row-buffer
#define EPSV   1e-5f

__global__ __launch_bounds__(NT, 4)
void lcn_fused_kernel(const float* __restrict__ x, float* __restrict__ out) {
    // XCD-aware bijective swizzle (gridDim.x = 512, %8==0): consecutive
    // chunks (same image, adjacent y) share an XCD's L2 for halo re-reads.
    const int cpx = gridDim.x >> 3;
    const int bid = (blockIdx.x & 7) * cpx + (blockIdx.x >> 3);

    const int chunk = bid & 15;            // 16 chunks of 64 rows per image
    const int b     = bid >> 4;
    const int y0    = chunk * SH;

    const float* img  = x   + (size_t)b * (IMG_H * IMG_W);
    float*       oimg = out + (size_t)b * (IMG_H * IMG_W);

    __shared__ float2 vbuf[RPP][LBUF];     // (vsum, vsumsq), transposed

    const int t    = threadIdx.x;
    const int wave = t >> 6;               // 0..7
    const int lane = t & 63;

    // Zero only the pads: iv in [0,16) -> phys iv*66; iv in [1040,1056)
    // -> phys (iv&15)*66 + 65. Interior republished every phase. The
    // phase-0 publish barrier orders these before any read.
    for (int i = t; i < RPP * 32; i += NT) {
        const int r = i >> 5, k = i & 31;
        float2* vb = vbuf[r];
        if (k < 16) vb[k * LROW] = make_float2(0.f, 0.f);
        else        vb[(k - 16) * LROW + (LROW - 1)] = make_float2(0.f, 0.f);
    }

    // ---- vertical warm-up: window(y0) over rows [y0-15, y0+15] ----
    const int c0 = 2 * t;                  // 2 consecutive cols per thread
    float vs0 = 0.f, vs1 = 0.f, vq0 = 0.f, vq1 = 0.f;
    for (int y = y0 - PAD; y <= y0 + PAD; ++y) {   // top: y0+15 <= 975 < H
        const int yc = max(y, 0);
        float2 v = *(const float2*)(img + (size_t)yc * IMG_W + c0);
        const float m = (y >= 0) ? 1.f : 0.f;
        v.x *= m; v.y *= m;
        vs0 += v.x; vq0 = fmaf(v.x, v.x, vq0);
        vs1 += v.y; vq1 = fmaf(v.y, v.y, vq1);
    }

    // Transposed publish indices for iv = c0+16, c0+17.
    const int iv0 = c0 + 16;
    const int wp0 = ((iv0    ) & 15) * LROW + ((iv0    ) >> 4);
    const int wp1 = ((iv0 + 1) & 15) * LROW + ((iv0 + 1) >> 4);

    const int   cbase = lane << 4;         // horizontal: 16 contiguous cols
    const float inv   = 1.0f / 961.0f;

    for (int ph = 0; ph < PHASES; ++ph) {
        const int yo = y0 + ph * RPP;

        // ---- batched branch-free slide loads (16 independent float2) ----
        float2 sb[RPP], ad[RPP];
        #pragma unroll
        for (int r = 0; r < RPP; ++r) {
            const int ys  = yo + r - PAD;
            const int ya  = yo + r + PAD + 1;
            const int ysc = max(ys, 0);
            const int yac = min(ya, IMG_H - 1);
            float2 vS = *(const float2*)(img + (size_t)ysc * IMG_W + c0);
            float2 vA = *(const float2*)(img + (size_t)yac * IMG_W + c0);
            const float mS = (ys >= 0)    ? 1.f : 0.f;
            const float mA = (ya < IMG_H) ? 1.f : 0.f;
            sb[r] = make_float2(vS.x * mS, vS.y * mS);
            ad[r] = make_float2(vA.x * mA, vA.y * mA);
        }

        // ---- publish + apply slides, RPP rows ----
        #pragma unroll
        for (int r = 0; r < RPP; ++r) {
            vbuf[r][wp0] = make_float2(vs0, vq0);
            vbuf[r][wp1] = make_float2(vs1, vq1);
            vs0 += ad[r].x - sb[r].x;
            vq0 = fmaf(ad[r].x, ad[r].x, vq0); vq0 = fmaf(-sb[r].x, sb[r].x, vq0);
            vs1 += ad[r].y - sb[r].y;
            vq1 = fmaf(ad[r].y, ad[r].y, vq1); vq1 = fmaf(-sb[r].y, sb[r].y, vq1);
        }
        __syncthreads();

        // ---- horizontal sliding window + pointwise (wave w -> row yo+w) ----
        {
            const int row = yo + wave;
            const float2* vr = &vbuf[wave][lane];
            float hs = 0.f, hq = 0.f;
            #pragma unroll
            for (int s = 1; s <= 31; ++s) {
                float2 v = vr[(s & 15) * LROW + (s >> 4)];
                hs += v.x; hq += v.y;
            }
            const float* xr = img + (size_t)row * IMG_W + cbase;
            float4 xa = ((const float4*)xr)[0];
            float4 xb = ((const float4*)xr)[1];
            float4 xc = ((const float4*)xr)[2];
            float4 xd = ((const float4*)xr)[3];
            float xs[16] = { xa.x, xa.y, xa.z, xa.w,  xb.x, xb.y, xb.z, xb.w,
                             xc.x, xc.y, xc.z, xc.w,  xd.x, xd.y, xd.z, xd.w };
            float res[16];
            #pragma unroll
            for (int j = 0; j < 16; ++j) {
                if (j > 0) {
                    float2 va  = vr[((j - 1) & 15) * LROW + 2];
                    float2 vsu = vr[(j & 15) * LROW];
                    hs += va.x - vsu.x;
                    hq += va.y - vsu.y;
                }
                const float mean = hs * inv;
                const float var  = fmaf(-mean, mean, hq * inv);
                const float stdv = sqrtf(fmaxf(var, EPSV));
                const float norm = (xs[j] - mean) *
                                   __builtin_amdgcn_rcpf(stdv + EPSV);
                res[j] = __builtin_amdgcn_rcpf(1.0f + __expf(-0.5f * norm));
            }
            float* orow = oimg + (size_t)row * IMG_W + cbase;
            ((float4*)orow)[0] = make_float4(res[0],  res[1],  res[2],  res[3]);
            ((float4*)orow)[1] = make_float4(res[4],  res[5],  res[6],  res[7]);
            ((float4*)orow)[2] = make_float4(res[8],  res[9],  res[10], res[11]);
            ((float4*)orow)[3] = make_float4(res[12], res[13], res[14], res[15]);
        }
        __syncthreads();                   // WAR: buffers rewritten next phase
    }
}

extern "C" void kernel_launch(void* const* d_in, const int* in_sizes, int n_in,
                              void* d_out, int out_size, void* d_ws, size_t ws_size,
                              hipStream_t stream) {
    (void)n_in; (void)out_size; (void)d_ws; (void)ws_size;
    const float* x = (const float*)d_in[0];
    float* out = (float*)d_out;
    const int B = in_sizes[0] / (IMG_H * IMG_W);   // 32
    dim3 grid(B * (IMG_H / SH));                   // 512 blocks
    lcn_fused_kernel<<<grid, NT, 0, stream>>>(x, out);
}